// Round 9
// baseline (393.696 us; speedup 1.0000x reference)
//
#include <hip/hip_runtime.h>
#include <hip/hip_bf16.h>
#include <math.h>

typedef unsigned short u16;
typedef __bf16 bf16x8_t __attribute__((ext_vector_type(8)));
typedef u16 u16x8 __attribute__((ext_vector_type(8)));
typedef u16 u16x4 __attribute__((ext_vector_type(4)));
typedef float f32x4 __attribute__((ext_vector_type(4)));

#define NH 12
#define LQ 2048
#define DM 768
#define DH 64
#define NR 4095           // 2L-1
#define LN2F 0.6931471805599453f

__device__ __forceinline__ u16 f2bf(float f){
  unsigned x = __float_as_uint(f);
  return (u16)((x + 0x7fffu + ((x >> 16) & 1u)) >> 16);   // RTNE
}
__device__ __forceinline__ float bf2f(u16 u){ return __uint_as_float(((unsigned)u) << 16); }

__device__ __forceinline__ f32x4 MFMA(u16x8 a, u16x8 b, f32x4 c){
  return __builtin_amdgcn_mfma_f32_16x16x32_bf16(
      __builtin_bit_cast(bf16x8_t, a), __builtin_bit_cast(bf16x8_t, b), c, 0, 0, 0);
}

// ---------------- gamma pdf table (unnormalized) + global max ----------------
__global__ void gamma_probs_kernel(float* __restrict__ gamtab,
                                   unsigned long long* __restrict__ gmax){
  int idx = blockIdx.x * 256 + threadIdx.x;   // 2048*128
  int x = idx >> 7, f = idx & 127;
  double fp1 = (double)(f + 1);
  double conc = 4.0 * fp1 * fp1;
  double rate = 0.25 * fp1;
  double xd = (double)x;
  double xlogy = (x > 0) ? (conc - 1.0) * log(xd) : 0.0;
  double logp = xlogy - rate * xd - lgamma(conc) + conc * log(rate);
  double p = exp(logp);
  gamtab[idx] = (float)p;
  double m = p;
  #pragma unroll
  for (int off = 1; off < 64; off <<= 1) m = fmax(m, __shfl_xor(m, off));
  if ((threadIdx.x & 63) == 0)
    atomicMax(gmax, (unsigned long long)__double_as_longlong(m));
}

// ---------------- positional encodings pe[4095][768] ----------------
__global__ void pe_kernel(const float* __restrict__ gamtab,
                          const unsigned long long* __restrict__ gmax,
                          float* __restrict__ pe){
  int idx = blockIdx.x * 256 + threadIdx.x;
  if (idx >= NR * DM) return;
  int p = idx / DM;
  int c = idx - p * DM;
  int f = c & 127;
  int kind = c >> 7;
  int pos = p - (LQ - 1);
  int apos = pos < 0 ? -pos : pos;
  float sgn = (pos > 0) ? 1.f : ((pos < 0) ? -1.f : 0.f);
  float v;
  int grp = kind >> 1;
  if (grp == 0){
    float hl = exp2f(3.f + 8.f * (float)f / 127.f);
    v = expf(-(LN2F / hl) * (float)apos);
  } else if (grp == 1){
    float cw = exp2f((float)(f + 1)) - 1.f;
    v = (cw > (float)apos) ? 1.f : 0.f;
  } else {
    float gm = (float)__longlong_as_double((long long)*gmax);
    v = gamtab[apos * 128 + f] / gm;
  }
  if (kind & 1) v *= sgn;
  pe[idx] = v;
}

// ---------------- fused q/k/v projection GEMM (grid.z picks input) ----------
#define GSTR 56
__launch_bounds__(256)
__global__ void proj3_kernel(const float* __restrict__ q_in, const float* __restrict__ k_in,
                             const float* __restrict__ v_in,
                             const float* __restrict__ Wq, const float* __restrict__ Wk,
                             const float* __restrict__ Wv,
                             u16* __restrict__ qh, u16* __restrict__ kh,
                             u16* __restrict__ vt){
  __shared__ u16 At[64 * GSTR];
  __shared__ u16 Wt[64 * GSTR];
  const int z = blockIdx.z;
  const float* A = (z == 0) ? q_in : (z == 1) ? k_in : v_in;
  const float* W = (z == 0) ? Wq : (z == 1) ? Wk : Wv;
  const float scale = (z == 0) ? 0.125f : 1.f;
  const int m0 = blockIdx.x * 64, n0 = blockIdx.y * 64;
  const int tid = threadIdx.x;
  const int w = tid >> 6, l = tid & 63, lr = l & 15, lg = l >> 4;
  const int moff = (w & 1) * 32, noff = (w >> 1) * 32;
  f32x4 acc[2][2] = {};
  const int arow = tid >> 2, akg = (tid & 3) * 8;
  const int wn = tid & 63, wkg = (tid >> 6) * 8;
  for (int k0 = 0; k0 < DM; k0 += 32){
    u16x8 av;
    {
      const float* ap = A + (size_t)(m0 + arow) * DM + k0 + akg;
      #pragma unroll
      for (int j = 0; j < 8; j++) av[j] = f2bf(ap[j]);
    }
    *(u16x8*)&At[arow * GSTR + akg] = av;
    u16x8 wv;
    #pragma unroll
    for (int i = 0; i < 8; i++)
      wv[i] = f2bf(W[(size_t)(k0 + wkg + i) * DM + n0 + wn]);
    *(u16x8*)&Wt[wn * GSTR + wkg] = wv;
    __syncthreads();
    u16x8 af0 = *(u16x8*)&At[(moff + lr) * GSTR + lg * 8];
    u16x8 af1 = *(u16x8*)&At[(moff + 16 + lr) * GSTR + lg * 8];
    u16x8 bf0 = *(u16x8*)&Wt[(noff + lr) * GSTR + lg * 8];
    u16x8 bf1 = *(u16x8*)&Wt[(noff + 16 + lr) * GSTR + lg * 8];
    acc[0][0] = MFMA(af0, bf0, acc[0][0]);
    acc[0][1] = MFMA(af0, bf1, acc[0][1]);
    acc[1][0] = MFMA(af1, bf0, acc[1][0]);
    acc[1][1] = MFMA(af1, bf1, acc[1][1]);
    __syncthreads();
  }
  u16* outb = (z == 0) ? qh : kh;
  #pragma unroll
  for (int mi = 0; mi < 2; mi++)
    #pragma unroll
    for (int ni = 0; ni < 2; ni++){
      if (z < 2){
        #pragma unroll
        for (int j = 0; j < 4; j++){
          int m = m0 + moff + mi * 16 + lg * 4 + j;
          int n = n0 + noff + ni * 16 + lr;
          outb[((size_t)(n >> 6) * LQ + m) * DH + (n & 63)] = f2bf(acc[mi][ni][j] * scale);
        }
      } else {
        int m = m0 + moff + mi * 16 + lg * 4;
        int n = n0 + noff + ni * 16 + lr;
        u16x4 ov;
        #pragma unroll
        for (int j = 0; j < 4; j++) ov[j] = f2bf(acc[mi][ni][j]);
        *(u16x4*)(vt + ((size_t)(n >> 6) * DH + (n & 63)) * LQ + m) = ov;
      }
    }
}

// ---------------- generic bf16-MFMA GEMM (rk + out-proj) ----------------
__launch_bounds__(256)
__global__ void gemm_kernel(const float* __restrict__ A, const float* __restrict__ W,
                            u16* __restrict__ outb, float* __restrict__ outf,
                            int M, float scale,
                            const float* __restrict__ bias, int mode){
  __shared__ u16 At[64 * GSTR];
  __shared__ u16 Wt[64 * GSTR];
  const int m0 = blockIdx.x * 64, n0 = blockIdx.y * 64;
  const int tid = threadIdx.x;
  const int w = tid >> 6, l = tid & 63, lr = l & 15, lg = l >> 4;
  const int moff = (w & 1) * 32, noff = (w >> 1) * 32;
  f32x4 acc[2][2] = {};
  const int arow = tid >> 2, akg = (tid & 3) * 8;
  const int wn = tid & 63, wkg = (tid >> 6) * 8;
  for (int k0 = 0; k0 < DM; k0 += 32){
    u16x8 av;
    if (m0 + arow < M){
      const float* ap = A + (size_t)(m0 + arow) * DM + k0 + akg;
      #pragma unroll
      for (int j = 0; j < 8; j++) av[j] = f2bf(ap[j]);
    } else {
      #pragma unroll
      for (int j = 0; j < 8; j++) av[j] = 0;
    }
    *(u16x8*)&At[arow * GSTR + akg] = av;
    u16x8 wv;
    #pragma unroll
    for (int i = 0; i < 8; i++)
      wv[i] = f2bf(W[(size_t)(k0 + wkg + i) * DM + n0 + wn]);
    *(u16x8*)&Wt[wn * GSTR + wkg] = wv;
    __syncthreads();
    u16x8 af0 = *(u16x8*)&At[(moff + lr) * GSTR + lg * 8];
    u16x8 af1 = *(u16x8*)&At[(moff + 16 + lr) * GSTR + lg * 8];
    u16x8 bf0 = *(u16x8*)&Wt[(noff + lr) * GSTR + lg * 8];
    u16x8 bf1 = *(u16x8*)&Wt[(noff + 16 + lr) * GSTR + lg * 8];
    acc[0][0] = MFMA(af0, bf0, acc[0][0]);
    acc[0][1] = MFMA(af0, bf1, acc[0][1]);
    acc[1][0] = MFMA(af1, bf0, acc[1][0]);
    acc[1][1] = MFMA(af1, bf1, acc[1][1]);
    __syncthreads();
  }
  #pragma unroll
  for (int mi = 0; mi < 2; mi++)
    #pragma unroll
    for (int ni = 0; ni < 2; ni++)
      #pragma unroll
      for (int j = 0; j < 4; j++){
        int m = m0 + moff + mi * 16 + lg * 4 + j;
        int n = n0 + noff + ni * 16 + lr;
        if (m < M){
          float v = acc[mi][ni][j] * scale;
          if (mode == 1){
            outf[(size_t)m * DM + n] = v + bias[n];
          } else {
            outb[((size_t)(n >> 6) * M + m) * DH + (n & 63)] = f2bf(v);
          }
        }
      }
}

// ---------------- fused rel-pos attention, QBLK=16, two-sweep softmax --------
// One WG = 1 head x 16 q-rows, 8 waves; wave w owns k-slice [w*256, w*256+256).
// Sweep 1: QK^T + band-gather (band stashed in 32 packed VGPRs) -> running max.
// Sweep 2: recompute QK^T (MFMA cheap), exp, sum, P -> LDS.  S never resident.
#define QB 16
#define RPSTR 2184
#define SMEM_ATTN (QB * RPSTR * 2 + 1024)
__launch_bounds__(512, 4)
__global__ void attn_kernel(const u16* __restrict__ qh, const u16* __restrict__ kh,
                            const u16* __restrict__ vt, const u16* __restrict__ rk,
                            const int* __restrict__ mask,
                            const float* __restrict__ r_w, const float* __restrict__ r_r,
                            float* __restrict__ map, float* __restrict__ att){
  extern __shared__ char smem[];
  u16* RP = (u16*)smem;
  float* redm = (float*)(smem + QB * RPSTR * 2);   // [8][16]
  float* redl = redm + 128;                        // [8][16]
  const int h = blockIdx.y, q0 = blockIdx.x * QB;
  const int tid = threadIdx.x, w = tid >> 6, l = tid & 63, lr = l & 15, lg = l >> 4;
  const int roff = (LQ - 1) - q0 - (QB - 1);       // 2032 - q0

  // phase 0: A fragments a1=(qh+r_w), a2=(qh+r_r)  (qh pre-scaled by 1/8)
  u16x8 a1[2], a2[2];
  #pragma unroll
  for (int kc = 0; kc < 2; kc++){
    u16x8 qv = *(const u16x8*)(qh + (size_t)(h * LQ + q0 + lr) * DH + kc * 32 + lg * 8);
    #pragma unroll
    for (int j = 0; j < 8; j++){
      int d = kc * 32 + lg * 8 + j;
      float f = bf2f(qv[j]);
      a1[kc][j] = f2bf(f + r_w[h * DH + d]);
      a2[kc][j] = f2bf(f + r_r[h * DH + d]);
    }
  }

  // phase 1: rel band R[q][j] = a2[q] . rk[roff + j], wave slice 17 tiles
  const int jb = w * 272;
  #pragma unroll
  for (int jt = 0; jt < 17; jt++){
    int r = roff + jb + jt * 16 + lr;
    if (r > NR - 1) r = NR - 1;     // clamped tail never gathered
    const u16* rp = rk + (size_t)(h * NR + r) * DH + lg * 8;
    u16x8 b0 = *(const u16x8*)(rp);
    u16x8 b1 = *(const u16x8*)(rp + 32);
    f32x4 racc = {};
    racc = MFMA(a2[0], b0, racc);
    racc = MFMA(a2[1], b1, racc);
    #pragma unroll
    for (int j = 0; j < 4; j++)
      RP[(lg * 4 + j) * RPSTR + jb + jt * 16 + lr] = f2bf(racc[j]);
  }
  __syncthreads();

  // sweep 1: content logits + band gather (stash) + mask -> running max only
  const int kb = w * 256;
  float fm[4] = {-3.0e38f, -3.0e38f, -3.0e38f, -3.0e38f};
  unsigned bnd[32];
  unsigned mbits = 0;
  #pragma unroll
  for (int nt = 0; nt < 16; nt++){
    const u16* kp = kh + (size_t)(h * LQ + kb + nt * 16 + lr) * DH + lg * 8;
    u16x8 b0 = *(const u16x8*)(kp);
    u16x8 b1 = *(const u16x8*)(kp + 32);
    f32x4 sv = {};
    sv = MFMA(a1[0], b0, sv);
    sv = MFMA(a1[1], b1, sv);
    int kg = kb + nt * 16 + lr;
    int mv = mask[kg];
    mbits |= ((unsigned)(mv & 1)) << nt;
    unsigned p0 = 0, p1 = 0;
    #pragma unroll
    for (int j = 0; j < 4; j++){
      int ql = lg * 4 + j;
      u16 bv = RP[ql * RPSTR + kg + (QB - 1) - ql];
      if (j < 2) p0 |= ((unsigned)bv) << (16 * j);
      else       p1 |= ((unsigned)bv) << (16 * (j - 2));
      float x = sv[j] + bf2f(bv);
      x = (mv == 1) ? -10000.f : x;
      fm[j] = fmaxf(fm[j], x);
    }
    bnd[nt * 2] = p0;
    bnd[nt * 2 + 1] = p1;
  }
  #pragma unroll
  for (int j = 0; j < 4; j++){
    float mx = fm[j];
    #pragma unroll
    for (int off = 1; off < 16; off <<= 1) mx = fmaxf(mx, __shfl_xor(mx, off));
    if (lr == 0) redm[w * QB + lg * 4 + j] = mx;
  }
  __syncthreads();
  #pragma unroll
  for (int j = 0; j < 4; j++){
    int ql = lg * 4 + j;
    float mx = redm[ql];
    #pragma unroll
    for (int w2 = 1; w2 < 8; w2++) mx = fmaxf(mx, redm[w2 * QB + ql]);
    fm[j] = mx;
  }

  // sweep 2: recompute logits, exp, accumulate sum, store P (band from regs)
  float ls[4] = {0.f, 0.f, 0.f, 0.f};
  #pragma unroll
  for (int nt = 0; nt < 16; nt++){
    const u16* kp = kh + (size_t)(h * LQ + kb + nt * 16 + lr) * DH + lg * 8;
    u16x8 b0 = *(const u16x8*)(kp);
    u16x8 b1 = *(const u16x8*)(kp + 32);
    f32x4 sv = {};
    sv = MFMA(a1[0], b0, sv);
    sv = MFMA(a1[1], b1, sv);
    int kg = kb + nt * 16 + lr;
    int msk = (mbits >> nt) & 1;
    unsigned p0 = bnd[nt * 2], p1 = bnd[nt * 2 + 1];
    #pragma unroll
    for (int j = 0; j < 4; j++){
      u16 bv = (u16)((j < 2 ? (p0 >> (16 * j)) : (p1 >> (16 * (j - 2)))) & 0xffffu);
      float x = sv[j] + bf2f(bv);
      x = msk ? -10000.f : x;
      float p = __expf(x - fm[j]);
      ls[j] += p;
      RP[(lg * 4 + j) * RPSTR + kg] = f2bf(p);
    }
  }
  #pragma unroll
  for (int j = 0; j < 4; j++){
    float s = ls[j];
    #pragma unroll
    for (int off = 1; off < 16; off <<= 1) s += __shfl_xor(s, off);
    if (lr == 0) redl[w * QB + lg * 4 + j] = s;
  }
  __syncthreads();
  float inv[4];
  #pragma unroll
  for (int j = 0; j < 4; j++){
    int ql = lg * 4 + j;
    float d = redl[ql];
    #pragma unroll
    for (int w2 = 1; w2 < 8; w2++) d += redl[w2 * QB + ql];
    inv[j] = 1.f / d;
  }

  // normalized map write (f32, output 1) — issued before PV so stores drain
  // under the PV MFMAs. 32 threads per q-row.
  {
    int qrow = tid >> 5, cb = (tid & 31) * 8;
    float dsum = redl[qrow];
    #pragma unroll
    for (int w2 = 1; w2 < 8; w2++) dsum += redl[w2 * QB + qrow];
    float invr = 1.f / dsum;
    float* mrow = map + (size_t)(h * LQ + q0 + qrow) * LQ;
    #pragma unroll
    for (int it = 0; it < 8; it++){
      int c = cb + it * 256;
      u16x8 pv = *(u16x8*)&RP[qrow * RPSTR + c];
      f32x4 o0, o1;
      #pragma unroll
      for (int j = 0; j < 4; j++){
        o0[j] = bf2f(pv[j]) * invr;
        o1[j] = bf2f(pv[4 + j]) * invr;
      }
      *(f32x4*)(mrow + c) = o0;
      *(f32x4*)(mrow + c + 4) = o1;
    }
  }

  // PV (A-frags = P rows lr from LDS, B-frags = vt[h][d][k] contiguous)
  f32x4 o[4] = {};
  #pragma unroll
  for (int kc2 = 0; kc2 < 8; kc2++){
    u16x8 pa = *(u16x8*)&RP[lr * RPSTR + kb + kc2 * 32 + lg * 8];
    #pragma unroll
    for (int ni = 0; ni < 4; ni++){
      u16x8 vv = *(const u16x8*)(vt + (size_t)(h * DH + ni * 16 + lr) * LQ + kb + kc2 * 32 + lg * 8);
      o[ni] = MFMA(pa, vv, o[ni]);
    }
  }
  __syncthreads();

  // cross-wave O reduction (overlays RP region)
  float* Op = (float*)smem;    // [8][16][64]
  #pragma unroll
  for (int ni = 0; ni < 4; ni++)
    #pragma unroll
    for (int j = 0; j < 4; j++)
      Op[(w * QB + lg * 4 + j) * 64 + ni * 16 + lr] = o[ni][j] * inv[j];
  __syncthreads();
  {
    int q = tid >> 5, dg = (tid & 31) * 2;
    float acc0 = 0.f, acc1 = 0.f;
    #pragma unroll
    for (int w2 = 0; w2 < 8; w2++){
      acc0 += Op[(w2 * QB + q) * 64 + dg];
      acc1 += Op[(w2 * QB + q) * 64 + dg + 1];
    }
    float* ap = att + (size_t)(q0 + q) * DM + h * DH + dg;
    ap[0] = acc0;
    ap[1] = acc1;
  }
}

extern "C" void kernel_launch(void* const* d_in, const int* in_sizes, int n_in,
                              void* d_out, int out_size, void* d_ws, size_t ws_size,
                              hipStream_t stream){
  const float* v_in = (const float*)d_in[0];
  const float* k_in = (const float*)d_in[1];
  const float* q_in = (const float*)d_in[2];
  const int*   mask = (const int*)d_in[3];
  const float* Wq   = (const float*)d_in[4];
  const float* Wk   = (const float*)d_in[5];
  const float* Wv   = (const float*)d_in[6];
  const float* Wrk  = (const float*)d_in[7];
  const float* r_w  = (const float*)d_in[8];
  const float* r_r  = (const float*)d_in[9];
  const float* Wo   = (const float*)d_in[10];
  const float* bo   = (const float*)d_in[11];

  char* ws = (char*)d_ws;
  u16* qh = (u16*)(ws + 0);              // [12][2048][64] bf16
  u16* kh = (u16*)(ws + 3145728);
  u16* vt = (u16*)(ws + 6291456);        // [12][64][2048] bf16
  u16* rk = (u16*)(ws + 9437184);        // [12][4095][64] bf16
  float* pe = (float*)(ws + 15727104);   // [4095][768] f32
  float* att = (float*)(ws + 28306944);  // [2048][768] f32
  float* gamtab = (float*)(ws + 34598400);           // [2048][128] f32
  unsigned long long* gmax = (unsigned long long*)(ws + 35646976);

  float* out0 = (float*)d_out;                     // [2048][768] f32
  float* map  = out0 + (size_t)LQ * DM;            // [12][2048][2048] f32

  hipMemsetAsync(gmax, 0, 8, stream);
  gamma_probs_kernel<<<1024, 256, 0, stream>>>(gamtab, gmax);
  pe_kernel<<<(NR * DM + 255) / 256, 256, 0, stream>>>(gamtab, gmax, pe);

  proj3_kernel<<<dim3(32, 12, 3), 256, 0, stream>>>(q_in, k_in, v_in, Wq, Wk, Wv,
                                                    qh, kh, vt);
  gemm_kernel<<<dim3(64, 12), 256, 0, stream>>>(pe, Wrk, rk, nullptr, NR, 1.f, nullptr, 0);

  hipFuncSetAttribute((const void*)attn_kernel,
                      hipFuncAttributeMaxDynamicSharedMemorySize, SMEM_ATTN);
  attn_kernel<<<dim3(LQ / QB, 12), 512, SMEM_ATTN, stream>>>(qh, kh, vt, rk, mask,
                                                             r_w, r_r, map, att);
  gemm_kernel<<<dim3(32, 12), 256, 0, stream>>>(att, Wo, nullptr, out0, LQ, 1.f, bo, 1);
}

// Round 10
// 317.599 us; speedup vs baseline: 1.2396x; 1.2396x over previous
//
#include <hip/hip_runtime.h>
#include <hip/hip_bf16.h>
#include <math.h>

typedef unsigned short u16;
typedef __bf16 bf16x8_t __attribute__((ext_vector_type(8)));
typedef u16 u16x8 __attribute__((ext_vector_type(8)));
typedef u16 u16x4 __attribute__((ext_vector_type(4)));
typedef float f32x4 __attribute__((ext_vector_type(4)));

#define NH 12
#define LQ 2048
#define DM 768
#define DH 64
#define NR 4095           // 2L-1
#define LN2F 0.6931471805599453f

__device__ __forceinline__ u16 f2bf(float f){
  unsigned x = __float_as_uint(f);
  return (u16)((x + 0x7fffu + ((x >> 16) & 1u)) >> 16);   // RTNE
}
__device__ __forceinline__ float bf2f(u16 u){ return __uint_as_float(((unsigned)u) << 16); }

__device__ __forceinline__ f32x4 MFMA(u16x8 a, u16x8 b, f32x4 c){
  return __builtin_amdgcn_mfma_f32_16x16x32_bf16(
      __builtin_bit_cast(bf16x8_t, a), __builtin_bit_cast(bf16x8_t, b), c, 0, 0, 0);
}

// ---------------- gamma pdf table (unnormalized) + global max ----------------
__global__ void gamma_probs_kernel(float* __restrict__ gamtab,
                                   unsigned long long* __restrict__ gmax){
  int idx = blockIdx.x * 256 + threadIdx.x;   // 2048*128
  int x = idx >> 7, f = idx & 127;
  double fp1 = (double)(f + 1);
  double conc = 4.0 * fp1 * fp1;
  double rate = 0.25 * fp1;
  double xd = (double)x;
  double xlogy = (x > 0) ? (conc - 1.0) * log(xd) : 0.0;
  double logp = xlogy - rate * xd - lgamma(conc) + conc * log(rate);
  double p = exp(logp);
  gamtab[idx] = (float)p;
  double m = p;
  #pragma unroll
  for (int off = 1; off < 64; off <<= 1) m = fmax(m, __shfl_xor(m, off));
  if ((threadIdx.x & 63) == 0)
    atomicMax(gmax, (unsigned long long)__double_as_longlong(m));
}

// ---------------- positional encodings pe[4095][768] ----------------
__global__ void pe_kernel(const float* __restrict__ gamtab,
                          const unsigned long long* __restrict__ gmax,
                          float* __restrict__ pe){
  int idx = blockIdx.x * 256 + threadIdx.x;
  if (idx >= NR * DM) return;
  int p = idx / DM;
  int c = idx - p * DM;
  int f = c & 127;
  int kind = c >> 7;
  int pos = p - (LQ - 1);
  int apos = pos < 0 ? -pos : pos;
  float sgn = (pos > 0) ? 1.f : ((pos < 0) ? -1.f : 0.f);
  float v;
  int grp = kind >> 1;
  if (grp == 0){
    float hl = exp2f(3.f + 8.f * (float)f / 127.f);
    v = expf(-(LN2F / hl) * (float)apos);
  } else if (grp == 1){
    float cw = exp2f((float)(f + 1)) - 1.f;
    v = (cw > (float)apos) ? 1.f : 0.f;
  } else {
    float gm = (float)__longlong_as_double((long long)*gmax);
    v = gamtab[apos * 128 + f] / gm;
  }
  if (kind & 1) v *= sgn;
  pe[idx] = v;
}

// ---------------- fused q/k/v projection GEMM (grid.z picks input) ----------
#define GSTR 56
__launch_bounds__(256)
__global__ void proj3_kernel(const float* __restrict__ q_in, const float* __restrict__ k_in,
                             const float* __restrict__ v_in,
                             const float* __restrict__ Wq, const float* __restrict__ Wk,
                             const float* __restrict__ Wv,
                             u16* __restrict__ qh, u16* __restrict__ kh,
                             u16* __restrict__ vt){
  __shared__ u16 At[64 * GSTR];
  __shared__ u16 Wt[64 * GSTR];
  const int z = blockIdx.z;
  const float* A = (z == 0) ? q_in : (z == 1) ? k_in : v_in;
  const float* W = (z == 0) ? Wq : (z == 1) ? Wk : Wv;
  const float scale = (z == 0) ? 0.125f : 1.f;
  const int m0 = blockIdx.x * 64, n0 = blockIdx.y * 64;
  const int tid = threadIdx.x;
  const int w = tid >> 6, l = tid & 63, lr = l & 15, lg = l >> 4;
  const int moff = (w & 1) * 32, noff = (w >> 1) * 32;
  f32x4 acc[2][2] = {};
  const int arow = tid >> 2, akg = (tid & 3) * 8;
  const int wn = tid & 63, wkg = (tid >> 6) * 8;
  for (int k0 = 0; k0 < DM; k0 += 32){
    u16x8 av;
    {
      const float* ap = A + (size_t)(m0 + arow) * DM + k0 + akg;
      #pragma unroll
      for (int j = 0; j < 8; j++) av[j] = f2bf(ap[j]);
    }
    *(u16x8*)&At[arow * GSTR + akg] = av;
    u16x8 wv;
    #pragma unroll
    for (int i = 0; i < 8; i++)
      wv[i] = f2bf(W[(size_t)(k0 + wkg + i) * DM + n0 + wn]);
    *(u16x8*)&Wt[wn * GSTR + wkg] = wv;
    __syncthreads();
    u16x8 af0 = *(u16x8*)&At[(moff + lr) * GSTR + lg * 8];
    u16x8 af1 = *(u16x8*)&At[(moff + 16 + lr) * GSTR + lg * 8];
    u16x8 bf0 = *(u16x8*)&Wt[(noff + lr) * GSTR + lg * 8];
    u16x8 bf1 = *(u16x8*)&Wt[(noff + 16 + lr) * GSTR + lg * 8];
    acc[0][0] = MFMA(af0, bf0, acc[0][0]);
    acc[0][1] = MFMA(af0, bf1, acc[0][1]);
    acc[1][0] = MFMA(af1, bf0, acc[1][0]);
    acc[1][1] = MFMA(af1, bf1, acc[1][1]);
    __syncthreads();
  }
  u16* outb = (z == 0) ? qh : kh;
  #pragma unroll
  for (int mi = 0; mi < 2; mi++)
    #pragma unroll
    for (int ni = 0; ni < 2; ni++){
      if (z < 2){
        #pragma unroll
        for (int j = 0; j < 4; j++){
          int m = m0 + moff + mi * 16 + lg * 4 + j;
          int n = n0 + noff + ni * 16 + lr;
          outb[((size_t)(n >> 6) * LQ + m) * DH + (n & 63)] = f2bf(acc[mi][ni][j] * scale);
        }
      } else {
        int m = m0 + moff + mi * 16 + lg * 4;
        int n = n0 + noff + ni * 16 + lr;
        u16x4 ov;
        #pragma unroll
        for (int j = 0; j < 4; j++) ov[j] = f2bf(acc[mi][ni][j]);
        *(u16x4*)(vt + ((size_t)(n >> 6) * DH + (n & 63)) * LQ + m) = ov;
      }
    }
}

// ---------------- generic bf16-MFMA GEMM (rk + out-proj) ----------------
__launch_bounds__(256)
__global__ void gemm_kernel(const float* __restrict__ A, const float* __restrict__ W,
                            u16* __restrict__ outb, float* __restrict__ outf,
                            int M, float scale,
                            const float* __restrict__ bias, int mode){
  __shared__ u16 At[64 * GSTR];
  __shared__ u16 Wt[64 * GSTR];
  const int m0 = blockIdx.x * 64, n0 = blockIdx.y * 64;
  const int tid = threadIdx.x;
  const int w = tid >> 6, l = tid & 63, lr = l & 15, lg = l >> 4;
  const int moff = (w & 1) * 32, noff = (w >> 1) * 32;
  f32x4 acc[2][2] = {};
  const int arow = tid >> 2, akg = (tid & 3) * 8;
  const int wn = tid & 63, wkg = (tid >> 6) * 8;
  for (int k0 = 0; k0 < DM; k0 += 32){
    u16x8 av;
    if (m0 + arow < M){
      const float* ap = A + (size_t)(m0 + arow) * DM + k0 + akg;
      #pragma unroll
      for (int j = 0; j < 8; j++) av[j] = f2bf(ap[j]);
    } else {
      #pragma unroll
      for (int j = 0; j < 8; j++) av[j] = 0;
    }
    *(u16x8*)&At[arow * GSTR + akg] = av;
    u16x8 wv;
    #pragma unroll
    for (int i = 0; i < 8; i++)
      wv[i] = f2bf(W[(size_t)(k0 + wkg + i) * DM + n0 + wn]);
    *(u16x8*)&Wt[wn * GSTR + wkg] = wv;
    __syncthreads();
    u16x8 af0 = *(u16x8*)&At[(moff + lr) * GSTR + lg * 8];
    u16x8 af1 = *(u16x8*)&At[(moff + 16 + lr) * GSTR + lg * 8];
    u16x8 bf0 = *(u16x8*)&Wt[(noff + lr) * GSTR + lg * 8];
    u16x8 bf1 = *(u16x8*)&Wt[(noff + 16 + lr) * GSTR + lg * 8];
    acc[0][0] = MFMA(af0, bf0, acc[0][0]);
    acc[0][1] = MFMA(af0, bf1, acc[0][1]);
    acc[1][0] = MFMA(af1, bf0, acc[1][0]);
    acc[1][1] = MFMA(af1, bf1, acc[1][1]);
    __syncthreads();
  }
  #pragma unroll
  for (int mi = 0; mi < 2; mi++)
    #pragma unroll
    for (int ni = 0; ni < 2; ni++)
      #pragma unroll
      for (int j = 0; j < 4; j++){
        int m = m0 + moff + mi * 16 + lg * 4 + j;
        int n = n0 + noff + ni * 16 + lr;
        if (m < M){
          float v = acc[mi][ni][j] * scale;
          if (mode == 1){
            outf[(size_t)m * DM + n] = v + bias[n];
          } else {
            outb[((size_t)(n >> 6) * M + m) * DH + (n & 63)] = f2bf(v);
          }
        }
      }
}

// ---------------- fused rel-pos attention, QBLK=16, wave-local band slabs ----
// Flat grid 1536, XCD-swizzled. One WG = 1 head x 16 q-rows, 8 waves; wave w
// owns k-slice [w*256, w*256+256) and a private band slab [16][280] covering
// band cols [kb, kb+272). No cross-wave band sharing -> no race, 3 barriers.
// S (16x256 per wave) lives in MFMA accumulators (AGPRs).
#define QB 16
#define SSTR 280
#define SLAB (QB * SSTR)                       // u16 per wave slab
#define SMEM_ATTN (8 * SLAB * 2 + 1024)        // 71680 + red arrays
__launch_bounds__(512, 4)
__global__ void attn_kernel(const u16* __restrict__ qh, const u16* __restrict__ kh,
                            const u16* __restrict__ vt, const u16* __restrict__ rk,
                            const int* __restrict__ mask,
                            const float* __restrict__ r_w, const float* __restrict__ r_r,
                            float* __restrict__ map, float* __restrict__ att){
  extern __shared__ char smem[];
  u16* RP = (u16*)smem;                         // 8 slabs
  float* redm = (float*)(smem + 8 * SLAB * 2);  // [8][16]
  float* redl = redm + 128;                     // [8][16]
  // XCD swizzle: consecutive swz on one XCD -> same head resident in its L2
  const int bid = blockIdx.x;
  const int swz = (bid & 7) * 192 + (bid >> 3);
  const int h = swz >> 7, q0 = (swz & 127) * QB;
  const int tid = threadIdx.x, w = tid >> 6, l = tid & 63, lr = l & 15, lg = l >> 4;
  const int roff = (LQ - 1) - q0 - (QB - 1);    // 2032 - q0
  const int kb = w * 256;
  u16* slab = RP + w * SLAB;

  // phase 0: A fragments a1=(qh+r_w), a2=(qh+r_r)  (qh pre-scaled by 1/8)
  u16x8 a1[2], a2[2];
  #pragma unroll
  for (int kc = 0; kc < 2; kc++){
    u16x8 qv = *(const u16x8*)(qh + (size_t)(h * LQ + q0 + lr) * DH + kc * 32 + lg * 8);
    #pragma unroll
    for (int j = 0; j < 8; j++){
      int d = kc * 32 + lg * 8 + j;
      float f = bf2f(qv[j]);
      a1[kc][j] = f2bf(f + r_w[h * DH + d]);
      a2[kc][j] = f2bf(f + r_r[h * DH + d]);
    }
  }

  // loop 1: band slab — 17 tiles covering cols [kb, kb+272)
  #pragma unroll 4
  for (int t = 0; t < 17; t++){
    int r = roff + kb + t * 16 + lr;
    if (r > NR - 1) r = NR - 1;                 // only the never-gathered corner
    const u16* rp = rk + (size_t)(h * NR + r) * DH + lg * 8;
    u16x8 b0 = *(const u16x8*)(rp);
    u16x8 b1 = *(const u16x8*)(rp + 32);
    f32x4 racc = {};
    racc = MFMA(a2[0], b0, racc);
    racc = MFMA(a2[1], b1, racc);
    #pragma unroll
    for (int j = 0; j < 4; j++)
      slab[(lg * 4 + j) * SSTR + t * 16 + lr] = f2bf(racc[j]);
  }
  __asm__ volatile("s_waitcnt lgkmcnt(0)" ::: "memory");   // wave-local slab ready
  __builtin_amdgcn_sched_barrier(0);

  // loop 2: content logits + wave-local band gather + mask -> S in AGPRs
  f32x4 s[16];
  #pragma unroll
  for (int nt = 0; nt < 16; nt++){
    const u16* kp = kh + (size_t)(h * LQ + kb + nt * 16 + lr) * DH + lg * 8;
    u16x8 b0 = *(const u16x8*)(kp);
    u16x8 b1 = *(const u16x8*)(kp + 32);
    f32x4 sv = {};
    sv = MFMA(a1[0], b0, sv);
    sv = MFMA(a1[1], b1, sv);
    int mv = mask[kb + nt * 16 + lr];
    #pragma unroll
    for (int j = 0; j < 4; j++){
      int ql = lg * 4 + j;
      float x = sv[j] + bf2f(slab[ql * SSTR + nt * 16 + lr + 15 - ql]);
      sv[j] = (mv == 1) ? -10000.f : x;
    }
    s[nt] = sv;
  }

  // softmax max reduce
  float fm[4];
  #pragma unroll
  for (int j = 0; j < 4; j++){
    float mx = -3.0e38f;
    #pragma unroll
    for (int nt = 0; nt < 16; nt++) mx = fmaxf(mx, s[nt][j]);
    #pragma unroll
    for (int off = 1; off < 16; off <<= 1) mx = fmaxf(mx, __shfl_xor(mx, off));
    if (lr == 0) redm[w * QB + lg * 4 + j] = mx;
  }
  __syncthreads();
  #pragma unroll
  for (int j = 0; j < 4; j++){
    int ql = lg * 4 + j;
    float mx = redm[ql];
    #pragma unroll
    for (int w2 = 1; w2 < 8; w2++) mx = fmaxf(mx, redm[w2 * QB + ql]);
    fm[j] = mx;
  }

  // exp + P store (overwrites band in own slab; band fully consumed)
  float ls[4] = {0.f, 0.f, 0.f, 0.f};
  #pragma unroll
  for (int nt = 0; nt < 16; nt++)
    #pragma unroll
    for (int j = 0; j < 4; j++){
      float p = __expf(s[nt][j] - fm[j]);
      ls[j] += p;
      slab[(lg * 4 + j) * SSTR + nt * 16 + lr] = f2bf(p);
    }
  #pragma unroll
  for (int j = 0; j < 4; j++){
    float sum = ls[j];
    #pragma unroll
    for (int off = 1; off < 16; off <<= 1) sum += __shfl_xor(sum, off);
    if (lr == 0) redl[w * QB + lg * 4 + j] = sum;
  }
  __syncthreads();
  float inv[4];
  #pragma unroll
  for (int j = 0; j < 4; j++){
    int ql = lg * 4 + j;
    float d = redl[ql];
    #pragma unroll
    for (int w2 = 1; w2 < 8; w2++) d += redl[w2 * QB + ql];
    inv[j] = 1.f / d;
  }

  // normalized map write (f32, output 1) — before PV so stores drain under MFMA
  {
    int qrow = tid >> 5, cb = (tid & 31) * 8;
    float dsum = redl[qrow];
    #pragma unroll
    for (int w2 = 1; w2 < 8; w2++) dsum += redl[w2 * QB + qrow];
    float invr = 1.f / dsum;
    float* mrow = map + (size_t)(h * LQ + q0 + qrow) * LQ;
    #pragma unroll
    for (int it = 0; it < 8; it++){
      u16x8 pv = *(u16x8*)&RP[it * SLAB + qrow * SSTR + cb];
      f32x4 o0, o1;
      #pragma unroll
      for (int j = 0; j < 4; j++){
        o0[j] = bf2f(pv[j]) * invr;
        o1[j] = bf2f(pv[4 + j]) * invr;
      }
      int c = cb + it * 256;
      *(f32x4*)(mrow + c) = o0;
      *(f32x4*)(mrow + c + 4) = o1;
    }
  }

  // PV (A-frags = P rows from own slab, B-frags = vt[h][d][k] contiguous)
  f32x4 o[4] = {};
  #pragma unroll
  for (int kc2 = 0; kc2 < 8; kc2++){
    u16x8 pa = *(u16x8*)&slab[lr * SSTR + kc2 * 32 + lg * 8];
    #pragma unroll
    for (int ni = 0; ni < 4; ni++){
      u16x8 vv = *(const u16x8*)(vt + (size_t)(h * DH + ni * 16 + lr) * LQ + kb + kc2 * 32 + lg * 8);
      o[ni] = MFMA(pa, vv, o[ni]);
    }
  }
  __syncthreads();

  // cross-wave O reduction (overlays slabs)
  float* Op = (float*)smem;    // [8][16][64]
  #pragma unroll
  for (int ni = 0; ni < 4; ni++)
    #pragma unroll
    for (int j = 0; j < 4; j++)
      Op[(w * QB + lg * 4 + j) * 64 + ni * 16 + lr] = o[ni][j] * inv[j];
  __syncthreads();
  {
    int q = tid >> 5, dg = (tid & 31) * 2;
    float acc0 = 0.f, acc1 = 0.f;
    #pragma unroll
    for (int w2 = 0; w2 < 8; w2++){
      acc0 += Op[(w2 * QB + q) * 64 + dg];
      acc1 += Op[(w2 * QB + q) * 64 + dg + 1];
    }
    float* ap = att + (size_t)(q0 + q) * DM + h * DH + dg;
    ap[0] = acc0;
    ap[1] = acc1;
  }
}

extern "C" void kernel_launch(void* const* d_in, const int* in_sizes, int n_in,
                              void* d_out, int out_size, void* d_ws, size_t ws_size,
                              hipStream_t stream){
  const float* v_in = (const float*)d_in[0];
  const float* k_in = (const float*)d_in[1];
  const float* q_in = (const float*)d_in[2];
  const int*   mask = (const int*)d_in[3];
  const float* Wq   = (const float*)d_in[4];
  const float* Wk   = (const float*)d_in[5];
  const float* Wv   = (const float*)d_in[6];
  const float* Wrk  = (const float*)d_in[7];
  const float* r_w  = (const float*)d_in[8];
  const float* r_r  = (const float*)d_in[9];
  const float* Wo   = (const float*)d_in[10];
  const float* bo   = (const float*)d_in[11];

  char* ws = (char*)d_ws;
  u16* qh = (u16*)(ws + 0);              // [12][2048][64] bf16
  u16* kh = (u16*)(ws + 3145728);
  u16* vt = (u16*)(ws + 6291456);        // [12][64][2048] bf16
  u16* rk = (u16*)(ws + 9437184);        // [12][4095][64] bf16
  float* pe = (float*)(ws + 15727104);   // [4095][768] f32
  float* att = (float*)(ws + 28306944);  // [2048][768] f32
  float* gamtab = (float*)(ws + 34598400);           // [2048][128] f32
  unsigned long long* gmax = (unsigned long long*)(ws + 35646976);

  float* out0 = (float*)d_out;                     // [2048][768] f32
  float* map  = out0 + (size_t)LQ * DM;            // [12][2048][2048] f32

  hipMemsetAsync(gmax, 0, 8, stream);
  gamma_probs_kernel<<<1024, 256, 0, stream>>>(gamtab, gmax);
  pe_kernel<<<(NR * DM + 255) / 256, 256, 0, stream>>>(gamtab, gmax, pe);

  proj3_kernel<<<dim3(32, 12, 3), 256, 0, stream>>>(q_in, k_in, v_in, Wq, Wk, Wv,
                                                    qh, kh, vt);
  gemm_kernel<<<dim3(64, 12), 256, 0, stream>>>(pe, Wrk, rk, nullptr, NR, 1.f, nullptr, 0);

  hipFuncSetAttribute((const void*)attn_kernel,
                      hipFuncAttributeMaxDynamicSharedMemorySize, SMEM_ATTN);
  attn_kernel<<<dim3((LQ / QB) * NH), 512, SMEM_ATTN, stream>>>(qh, kh, vt, rk, mask,
                                                                r_w, r_r, map, att);
  gemm_kernel<<<dim3(32, 12), 256, 0, stream>>>(att, Wo, nullptr, out0, LQ, 1.f, bo, 1);
}